// Round 5
// baseline (322.491 us; speedup 1.0000x reference)
//
#include <hip/hip_runtime.h>
#include <math.h>

#define IMG_H 2048
#define IMG_W 2048
#define TX 64
#define TY 32
#define HALO 3
#define TILE_H (TY + 2 * HALO)      // 38 halo rows
#define SIN_STR 76                  // dwords; 72 cols loaded + pad
#define VM_STR 76                   // vertical-max buffer stride (72 cols used)
#define CAND_CAP (1u << 20)
#define CBUF 1024

__device__ __forceinline__ float4 fmax4(float4 a, float4 b) {
    return make_float4(fmaxf(a.x, b.x), fmaxf(a.y, b.y), fmaxf(a.z, b.z), fmaxf(a.w, b.w));
}

// Order-preserving float->uint key: ascending float order == ascending uint order.
__device__ __forceinline__ unsigned f2key(unsigned u) {
    unsigned mask = (unsigned)(((int)u >> 31)) | 0x80000000u;
    return u ^ mask;
}
static inline unsigned f2key_host(float f) {
    union { float f; unsigned u; } c; c.f = f;
    unsigned mask = (unsigned)(((int)c.u >> 31)) | 0x80000000u;
    return c.u ^ mask;
}

// Block-wide exclusive scan over 256 values (Hillis-Steele, 8 steps).
__device__ __forceinline__ unsigned block_exscan(unsigned val, unsigned* tmp) {
    const int t = threadIdx.x;
    tmp[t] = val;
    __syncthreads();
#pragma unroll
    for (int off = 1; off < 256; off <<= 1) {
        unsigned v = (t >= off) ? tmp[t - off] : 0u;
        __syncthreads();
        tmp[t] += v;
        __syncthreads();
    }
    return tmp[t] - val;
}

// Find bin b such that sum(bins[0..b)) <= k < sum(bins[0..b]). bins length = 256*C.
template <int C>
__device__ __forceinline__ void find_crossing(const unsigned* bins, unsigned k,
                                              unsigned* tmp, unsigned* res) {
    unsigned s = 0;
#pragma unroll
    for (int j = 0; j < C; ++j) s += bins[threadIdx.x * C + j];
    unsigned ex = block_exscan(s, tmp);
    if (k >= ex && k < ex + s) {  // exactly one thread
        unsigned cum = ex;
        int b = threadIdx.x * C;
        while (cum + bins[b] <= k) { cum += bins[b]; ++b; }
        res[0] = (unsigned)b;
        res[1] = k - cum;
    }
    __syncthreads();
}

// ---- Pass 1: 2048-bin histogram of top-11 key bits + window candidate compaction ----
__global__ __launch_bounds__(256) void hist_window_kernel(
        const float4* __restrict__ x, int n4, unsigned* __restrict__ ghist,
        unsigned* __restrict__ ctrl, unsigned* __restrict__ candA,
        unsigned keyLo, unsigned keyHi) {
    __shared__ unsigned h[4 * 2048];   // per-wave private histograms
    __shared__ unsigned cbuf[CBUF];
    __shared__ unsigned ccnt, sbase, scnt;
    const int wave = threadIdx.x >> 6;
    unsigned* hw = &h[wave * 2048];
    for (int i = threadIdx.x; i < 4 * 2048; i += 256) h[i] = 0;
    if (threadIdx.x == 0) ccnt = 0;
    __syncthreads();
    const int stride = gridDim.x * blockDim.x;
    for (int i = blockIdx.x * blockDim.x + threadIdx.x; i < n4; i += stride) {
        float4 v = x[i];
        unsigned k0 = f2key(__float_as_uint(v.x));
        unsigned k1 = f2key(__float_as_uint(v.y));
        unsigned k2 = f2key(__float_as_uint(v.z));
        unsigned k3 = f2key(__float_as_uint(v.w));
        atomicAdd(&hw[k0 >> 21], 1u);
        atomicAdd(&hw[k1 >> 21], 1u);
        atomicAdd(&hw[k2 >> 21], 1u);
        atomicAdd(&hw[k3 >> 21], 1u);
        if (k0 > keyLo && k0 < keyHi) { unsigned p = atomicAdd(&ccnt, 1u); if (p < CBUF) cbuf[p] = k0; }
        if (k1 > keyLo && k1 < keyHi) { unsigned p = atomicAdd(&ccnt, 1u); if (p < CBUF) cbuf[p] = k1; }
        if (k2 > keyLo && k2 < keyHi) { unsigned p = atomicAdd(&ccnt, 1u); if (p < CBUF) cbuf[p] = k2; }
        if (k3 > keyLo && k3 < keyHi) { unsigned p = atomicAdd(&ccnt, 1u); if (p < CBUF) cbuf[p] = k3; }
    }
    __syncthreads();
    for (int b = threadIdx.x; b < 2048; b += 256) {
        unsigned s = h[b] + h[2048 + b] + h[4096 + b] + h[6144 + b];
        if (s) atomicAdd(&ghist[b], s);
    }
    if (threadIdx.x == 0) {
        unsigned c = ccnt;
        if (c > CBUF) { c = CBUF; atomicOr(&ctrl[3], 1u); }         // LDS buffer overflow
        unsigned base = atomicAdd(&ctrl[2], c);
        if (base + c > CAND_CAP) {                                   // global buffer overflow
            atomicOr(&ctrl[3], 1u);
            c = base < CAND_CAP ? CAND_CAP - base : 0;
        }
        sbase = base; scnt = c;
    }
    __syncthreads();
    for (unsigned i = threadIdx.x; i < scnt; i += 256) candA[sbase + i] = cbuf[i];
}

// ---- Find bucket containing rank k (parallel scan) + window-coverage check ----
__global__ __launch_bounds__(256) void find_bucket_kernel(
        const unsigned* __restrict__ ghist, unsigned k, unsigned* __restrict__ ctrl,
        unsigned keyLo, unsigned keyHi) {
    __shared__ unsigned lh[2048];
    __shared__ unsigned tmp[256];
    __shared__ unsigned res[2];
    for (int i = threadIdx.x; i < 2048; i += 256) lh[i] = ghist[i];
    __syncthreads();
    find_crossing<8>(lh, k, tmp, res);
    if (threadIdx.x == 0) {
        unsigned b = res[0];
        ctrl[0] = b;
        ctrl[1] = res[1];
        unsigned lo = b << 21, hi = (b << 21) + 0x1FFFFFu;
        // covered: every key of the median bucket lies strictly inside the window
        ctrl[4] = (lo > keyLo && hi < keyHi && ctrl[3] == 0u) ? 1u : 0u;
    }
}

// ---- Fallback compact (no-op when window covered the bucket) ----
__global__ __launch_bounds__(256) void compact_fallback_kernel(
        const float4* __restrict__ x, int n4, unsigned* __restrict__ ctrl,
        unsigned* __restrict__ candB) {
    if (ctrl[4]) return;  // covered -> launch-overhead only
    const unsigned bucket = ctrl[0];
    const int stride = gridDim.x * blockDim.x;
    for (int i = blockIdx.x * blockDim.x + threadIdx.x; i < n4; i += stride) {
        float4 v = x[i];
        unsigned ks[4] = { f2key(__float_as_uint(v.x)), f2key(__float_as_uint(v.y)),
                           f2key(__float_as_uint(v.z)), f2key(__float_as_uint(v.w)) };
#pragma unroll
        for (int j = 0; j < 4; ++j)
            if ((ks[j] >> 21) == bucket) {
                unsigned p = atomicAdd(&ctrl[5], 1u);
                if (p < CAND_CAP) candB[p] = ks[j];
            }
    }
}

// ---- Multi-block filter: candA (window, ~53k) -> candC (median bucket, ~200) ----
__global__ __launch_bounds__(256) void bucket_filter_kernel(
        const unsigned* __restrict__ ctrl_c, unsigned* __restrict__ ctrl,
        const unsigned* __restrict__ candA, unsigned* __restrict__ candC) {
    if (!ctrl_c[4]) return;  // fallback path: candB already holds bucket keys
    const unsigned bucket = ctrl_c[0];
    unsigned M = ctrl_c[2];
    if (M > CAND_CAP) M = CAND_CAP;
    const int stride = gridDim.x * blockDim.x;
    for (unsigned i = blockIdx.x * blockDim.x + threadIdx.x; i < M; i += stride) {
        unsigned key = candA[i];
        if ((key >> 21) == bucket) {
            unsigned p = atomicAdd(&ctrl[6], 1u);
            if (p < CAND_CAP) candC[p] = key;
        }
    }
}

// ---- Exact median among bucket candidates (single block, ~200 entries) ----
__global__ __launch_bounds__(256) void final_select_kernel(
        unsigned* __restrict__ ctrl, const unsigned* __restrict__ candC,
        const unsigned* __restrict__ candB, float* __restrict__ medp) {
    __shared__ unsigned h2[2048];
    __shared__ unsigned tmp[256];
    __shared__ unsigned res[2];
    const unsigned covered = ctrl[4];
    const unsigned* src = covered ? candC : candB;
    unsigned M = covered ? ctrl[6] : ctrl[5];
    if (M > CAND_CAP) M = CAND_CAP;
    const unsigned bucket = ctrl[0];
    const unsigned r = ctrl[1];

    // Level 2: key bits [20:10]
    for (int i = threadIdx.x; i < 2048; i += 256) h2[i] = 0;
    __syncthreads();
    for (unsigned i = threadIdx.x; i < M; i += 256) {
        unsigned key = src[i];
        if ((key >> 21) == bucket) atomicAdd(&h2[(key >> 10) & 0x7FFu], 1u);
    }
    __syncthreads();
    find_crossing<8>(h2, r, tmp, res);
    const unsigned pref = (bucket << 11) | res[0];
    const unsigned r2 = res[1];
    __syncthreads();

    // Level 3: key bits [9:0]
    for (int i = threadIdx.x; i < 1024; i += 256) h2[i] = 0;
    __syncthreads();
    for (unsigned i = threadIdx.x; i < M; i += 256) {
        unsigned key = src[i];
        if ((key >> 10) == pref) atomicAdd(&h2[key & 0x3FFu], 1u);
    }
    __syncthreads();
    find_crossing<4>(h2, r2, tmp, res);
    if (threadIdx.x == 0) {
        unsigned key = (pref << 10) | res[0];
        unsigned u = (key & 0x80000000u) ? (key ^ 0x80000000u) : ~key;
        *medp = __uint_as_float(u);
    }
}

// ---- Fused threshold + 7x7 maxpool + NMS: vertical-first separable max ----
// Tile: 64 wide x 32 tall. Halo tile: 38 rows x 72 cols (gx in [tx0-4, tx0+68)).
// Output col j <-> tile col j+4. vmax[r][c] = max over sin rows r..r+6 (out row r).
__global__ __launch_bounds__(256, 4) void nms_kernel(const float* __restrict__ x,
                                                     float* __restrict__ out,
                                                     const float* __restrict__ medp) {
    __shared__ __align__(16) float sin_[TILE_H * SIN_STR];  // 38x76 dwords = 11.5 KB
    __shared__ __align__(16) float vmax[TY * VM_STR];       // 32x76 dwords =  9.7 KB
    const float med = *medp;
    const int tx0 = blockIdx.x * TX;
    const int ty0 = blockIdx.y * TY;
    const size_t ib = (size_t)blockIdx.z * (size_t)(IMG_H * IMG_W);
    const float* img = x + ib;
    float* oimg = out + ib;
    const bool colsafe = (tx0 >= 4) && (tx0 + 68 <= IMG_W);

    // Phase 1: load 38x72 halo tile as float4, threshold on the fly.
    // Out-of-image -> -inf (pool padding; thr >= 0 so it never wins).
    for (int task = threadIdx.x; task < TILE_H * 18; task += 256) {
        int rr = task / 18;
        int c4 = task - rr * 18;
        int gy = ty0 + rr - HALO;
        int gx0 = tx0 - 4 + c4 * 4;
        float4 v;
        if ((unsigned)gy < (unsigned)IMG_H) {
            if (colsafe) {
                v = *(const float4*)(img + (size_t)gy * IMG_W + gx0);
                v.x = (v.x > med) ? v.x : 0.0f;
                v.y = (v.y > med) ? v.y : 0.0f;
                v.z = (v.z > med) ? v.z : 0.0f;
                v.w = (v.w > med) ? v.w : 0.0f;
            } else {
                float c[4];
#pragma unroll
                for (int j = 0; j < 4; ++j) {
                    int gx = gx0 + j;
                    if ((unsigned)gx < (unsigned)IMG_W) {
                        float xv = img[(size_t)gy * IMG_W + gx];
                        c[j] = (xv > med) ? xv : 0.0f;
                    } else c[j] = -INFINITY;
                }
                v = make_float4(c[0], c[1], c[2], c[3]);
            }
        } else {
            v = make_float4(-INFINITY, -INFINITY, -INFINITY, -INFINITY);
        }
        *(float4*)&sin_[rr * SIN_STR + c4 * 4] = v;
    }
    __syncthreads();

    // Phase 2: vertical 7-tap max, register sliding window.
    // 4 row-segments (8 out rows each) x 18 float4 cols = 72 tasks.
    // 14 b128 reads -> 8 out rows -> 8 b128 writes.
    for (int task = threadIdx.x; task < 4 * 18; task += 256) {
        int seg = task / 18;
        int c4 = task - seg * 18;
        int r0 = seg * 8;
        float4 v[14];
#pragma unroll
        for (int j = 0; j < 14; ++j) v[j] = *(const float4*)&sin_[(r0 + j) * SIN_STR + c4 * 4];
        float4 m2[13];
#pragma unroll
        for (int j = 0; j < 13; ++j) m2[j] = fmax4(v[j], v[j + 1]);
        float4 m4[11];
#pragma unroll
        for (int j = 0; j < 11; ++j) m4[j] = fmax4(m2[j], m2[j + 2]);
#pragma unroll
        for (int j = 0; j < 8; ++j)
            *(float4*)&vmax[(r0 + j) * VM_STR + c4 * 4] = fmax4(m4[j], m4[j + 3]);  // rows j..j+6
    }
    __syncthreads();

    // Phase 3: horizontal 7-tap max over vmax + NMS compare + float4 stores.
    // 32 rows x 4 col-segments of 16 outputs = 128 tasks.
    // 6 vmax b128 reads + 4 sin b128 reads -> 4 global float4 stores.
    for (int task = threadIdx.x; task < 32 * 4; task += 256) {
        int row = task >> 2;
        int s = task & 3;
        int c0 = s * 16;
        const float* p = &vmax[row * VM_STR + c0];
        float v[24];
#pragma unroll
        for (int b = 0; b < 6; ++b) {
            float4 q = *(const float4*)(p + 4 * b);
            v[4 * b] = q.x; v[4 * b + 1] = q.y; v[4 * b + 2] = q.z; v[4 * b + 3] = q.w;
        }
        float m2[22];
#pragma unroll
        for (int j = 1; j <= 21; ++j) m2[j] = fmaxf(v[j], v[j + 1]);
        float m4[20];
#pragma unroll
        for (int j = 1; j <= 19; ++j) m4[j] = fmaxf(m2[j], m2[j + 2]);
        const float* tc = &sin_[(row + HALO) * SIN_STR + c0 + 4];
        float* og = oimg + (size_t)(ty0 + row) * IMG_W + tx0 + c0;
#pragma unroll
        for (int b = 0; b < 4; ++b) {
            float4 t = *(const float4*)(tc + 4 * b);
            float4 o;
            o.x = (t.x == fmaxf(m4[4 * b + 1], m4[4 * b + 4])) ? t.x : 0.0f;
            o.y = (t.y == fmaxf(m4[4 * b + 2], m4[4 * b + 5])) ? t.y : 0.0f;
            o.z = (t.z == fmaxf(m4[4 * b + 3], m4[4 * b + 6])) ? t.z : 0.0f;
            o.w = (t.w == fmaxf(m4[4 * b + 4], m4[4 * b + 7])) ? t.w : 0.0f;
            *(float4*)(og + 4 * b) = o;
        }
    }
}

extern "C" void kernel_launch(void* const* d_in, const int* in_sizes, int n_in,
                              void* d_out, int out_size, void* d_ws, size_t ws_size,
                              hipStream_t stream) {
    const float* x = (const float*)d_in[0];
    float* out = (float*)d_out;
    const int n = in_sizes[0];                   // 8*2048*2048
    const int n4 = n / 4;
    const unsigned k = (unsigned)((n - 1) / 2);  // lower-median rank (0-indexed)

    unsigned char* ws = (unsigned char*)d_ws;
    unsigned* ghist = (unsigned*)ws;               // 2048 u32
    unsigned* ctrl = (unsigned*)(ws + 2048 * 4);   // [0]=bucket [1]=rank [2]=cntA [3]=ovf [4]=covered [5]=cntB [6]=cntC
    float* medp = (float*)(ctrl + 7);
    unsigned* candA = (unsigned*)(ws + 2048 * 4 + 64);
    unsigned* candB = candA + CAND_CAP;
    unsigned* candC = candB + CAND_CAP;
    const size_t reserved = 2048 * 4 + 64;

    // ws is re-poisoned to 0xAA before every timed launch: zero hist + control words.
    hipMemsetAsync(d_ws, 0, reserved, stream);

    // Window around the expected median of ~N(0,1) data: |x| < 0.002 (~9 sigma of
    // the sample-median distribution at n=33.5M). Coverage is verified exactly;
    // fallback pass handles arbitrary inputs.
    const float W = 0.002f;
    const unsigned keyLo = f2key_host(-W);
    const unsigned keyHi = f2key_host(W);

    hist_window_kernel<<<1024, 256, 0, stream>>>((const float4*)x, n4, ghist, ctrl, candA, keyLo, keyHi);
    find_bucket_kernel<<<1, 256, 0, stream>>>(ghist, k, ctrl, keyLo, keyHi);
    compact_fallback_kernel<<<1024, 256, 0, stream>>>((const float4*)x, n4, ctrl, candB);
    bucket_filter_kernel<<<64, 256, 0, stream>>>(ctrl, ctrl, candA, candC);
    final_select_kernel<<<1, 256, 0, stream>>>(ctrl, candC, candB, medp);

    dim3 grid(IMG_W / TX, IMG_H / TY, n / (IMG_H * IMG_W));
    nms_kernel<<<grid, 256, 0, stream>>>(x, out, medp);
}

// Round 6
// 311.569 us; speedup vs baseline: 1.0351x; 1.0351x over previous
//
#include <hip/hip_runtime.h>
#include <math.h>

#define IMG_H 2048
#define IMG_W 2048
#define TX 64
#define TY 32
#define HALO 3
#define TILE_H (TY + 2 * HALO)      // 38 halo rows
#define SIN_STR 76                  // dwords; 72 cols loaded + pad; verified conflict-free for b128
#define SHM_STR 68                  // dwords; 64 cols + pad; verified conflict-free for b128
#define CAND_CAP (1u << 20)
#define CBUF 1024

__device__ __forceinline__ float4 fmax4(float4 a, float4 b) {
    return make_float4(fmaxf(a.x, b.x), fmaxf(a.y, b.y), fmaxf(a.z, b.z), fmaxf(a.w, b.w));
}

// Order-preserving float->uint key: ascending float order == ascending uint order.
__device__ __forceinline__ unsigned f2key(unsigned u) {
    unsigned mask = (unsigned)(((int)u >> 31)) | 0x80000000u;
    return u ^ mask;
}
static inline unsigned f2key_host(float f) {
    union { float f; unsigned u; } c; c.f = f;
    unsigned mask = (unsigned)(((int)c.u >> 31)) | 0x80000000u;
    return c.u ^ mask;
}

// Block-wide exclusive scan over 256 values (Hillis-Steele, 8 steps).
__device__ __forceinline__ unsigned block_exscan(unsigned val, unsigned* tmp) {
    const int t = threadIdx.x;
    tmp[t] = val;
    __syncthreads();
#pragma unroll
    for (int off = 1; off < 256; off <<= 1) {
        unsigned v = (t >= off) ? tmp[t - off] : 0u;
        __syncthreads();
        tmp[t] += v;
        __syncthreads();
    }
    return tmp[t] - val;
}

// Find bin b such that sum(bins[0..b)) <= k < sum(bins[0..b]). bins length = 256*C.
template <int C>
__device__ __forceinline__ void find_crossing(const unsigned* bins, unsigned k,
                                              unsigned* tmp, unsigned* res) {
    unsigned s = 0;
#pragma unroll
    for (int j = 0; j < C; ++j) s += bins[threadIdx.x * C + j];
    unsigned ex = block_exscan(s, tmp);
    if (k >= ex && k < ex + s) {  // exactly one thread
        unsigned cum = ex;
        int b = threadIdx.x * C;
        while (cum + bins[b] <= k) { cum += bins[b]; ++b; }
        res[0] = (unsigned)b;
        res[1] = k - cum;
    }
    __syncthreads();
}

// ---- Pass 1: 2048-bin histogram of top-11 key bits + window candidate compaction ----
__global__ __launch_bounds__(256) void hist_window_kernel(
        const float4* __restrict__ x, int n4, unsigned* __restrict__ ghist,
        unsigned* __restrict__ ctrl, unsigned* __restrict__ candA,
        unsigned keyLo, unsigned keyHi) {
    __shared__ unsigned h[4 * 2048];   // per-wave private histograms
    __shared__ unsigned cbuf[CBUF];
    __shared__ unsigned ccnt, sbase, scnt;
    const int wave = threadIdx.x >> 6;
    unsigned* hw = &h[wave * 2048];
    for (int i = threadIdx.x; i < 4 * 2048; i += 256) h[i] = 0;
    if (threadIdx.x == 0) ccnt = 0;
    __syncthreads();
    const int stride = gridDim.x * blockDim.x;
    for (int i = blockIdx.x * blockDim.x + threadIdx.x; i < n4; i += stride) {
        float4 v = x[i];
        unsigned k0 = f2key(__float_as_uint(v.x));
        unsigned k1 = f2key(__float_as_uint(v.y));
        unsigned k2 = f2key(__float_as_uint(v.z));
        unsigned k3 = f2key(__float_as_uint(v.w));
        atomicAdd(&hw[k0 >> 21], 1u);
        atomicAdd(&hw[k1 >> 21], 1u);
        atomicAdd(&hw[k2 >> 21], 1u);
        atomicAdd(&hw[k3 >> 21], 1u);
        if (k0 > keyLo && k0 < keyHi) { unsigned p = atomicAdd(&ccnt, 1u); if (p < CBUF) cbuf[p] = k0; }
        if (k1 > keyLo && k1 < keyHi) { unsigned p = atomicAdd(&ccnt, 1u); if (p < CBUF) cbuf[p] = k1; }
        if (k2 > keyLo && k2 < keyHi) { unsigned p = atomicAdd(&ccnt, 1u); if (p < CBUF) cbuf[p] = k2; }
        if (k3 > keyLo && k3 < keyHi) { unsigned p = atomicAdd(&ccnt, 1u); if (p < CBUF) cbuf[p] = k3; }
    }
    __syncthreads();
    for (int b = threadIdx.x; b < 2048; b += 256) {
        unsigned s = h[b] + h[2048 + b] + h[4096 + b] + h[6144 + b];
        if (s) atomicAdd(&ghist[b], s);
    }
    if (threadIdx.x == 0) {
        unsigned c = ccnt;
        if (c > CBUF) { c = CBUF; atomicOr(&ctrl[3], 1u); }         // LDS buffer overflow
        unsigned base = atomicAdd(&ctrl[2], c);
        if (base + c > CAND_CAP) {                                   // global buffer overflow
            atomicOr(&ctrl[3], 1u);
            c = base < CAND_CAP ? CAND_CAP - base : 0;
        }
        sbase = base; scnt = c;
    }
    __syncthreads();
    for (unsigned i = threadIdx.x; i < scnt; i += 256) candA[sbase + i] = cbuf[i];
}

// ---- Find bucket containing rank k (parallel scan) + window-coverage check ----
__global__ __launch_bounds__(256) void find_bucket_kernel(
        const unsigned* __restrict__ ghist, unsigned k, unsigned* __restrict__ ctrl,
        unsigned keyLo, unsigned keyHi) {
    __shared__ unsigned lh[2048];
    __shared__ unsigned tmp[256];
    __shared__ unsigned res[2];
    for (int i = threadIdx.x; i < 2048; i += 256) lh[i] = ghist[i];
    __syncthreads();
    find_crossing<8>(lh, k, tmp, res);
    if (threadIdx.x == 0) {
        unsigned b = res[0];
        ctrl[0] = b;
        ctrl[1] = res[1];
        unsigned lo = b << 21, hi = (b << 21) + 0x1FFFFFu;
        // covered: every key of the median bucket lies strictly inside the window
        ctrl[4] = (lo > keyLo && hi < keyHi && ctrl[3] == 0u) ? 1u : 0u;
    }
}

// ---- Fallback compact (no-op when window covered the bucket) ----
__global__ __launch_bounds__(256) void compact_fallback_kernel(
        const float4* __restrict__ x, int n4, unsigned* __restrict__ ctrl,
        unsigned* __restrict__ candB) {
    if (ctrl[4]) return;  // covered -> launch-overhead only
    const unsigned bucket = ctrl[0];
    const int stride = gridDim.x * blockDim.x;
    for (int i = blockIdx.x * blockDim.x + threadIdx.x; i < n4; i += stride) {
        float4 v = x[i];
        unsigned ks[4] = { f2key(__float_as_uint(v.x)), f2key(__float_as_uint(v.y)),
                           f2key(__float_as_uint(v.z)), f2key(__float_as_uint(v.w)) };
#pragma unroll
        for (int j = 0; j < 4; ++j)
            if ((ks[j] >> 21) == bucket) {
                unsigned p = atomicAdd(&ctrl[5], 1u);
                if (p < CAND_CAP) candB[p] = ks[j];
            }
    }
}

// ---- Multi-block filter: candA (window, ~53k) -> candC (median bucket, ~200) ----
__global__ __launch_bounds__(256) void bucket_filter_kernel(
        const unsigned* __restrict__ ctrl_c, unsigned* __restrict__ ctrl,
        const unsigned* __restrict__ candA, unsigned* __restrict__ candC) {
    if (!ctrl_c[4]) return;  // fallback path: candB already holds bucket keys
    const unsigned bucket = ctrl_c[0];
    unsigned M = ctrl_c[2];
    if (M > CAND_CAP) M = CAND_CAP;
    const int stride = gridDim.x * blockDim.x;
    for (unsigned i = blockIdx.x * blockDim.x + threadIdx.x; i < M; i += stride) {
        unsigned key = candA[i];
        if ((key >> 21) == bucket) {
            unsigned p = atomicAdd(&ctrl[6], 1u);
            if (p < CAND_CAP) candC[p] = key;
        }
    }
}

// ---- Exact median among bucket candidates (single block, ~200 entries) ----
__global__ __launch_bounds__(256) void final_select_kernel(
        unsigned* __restrict__ ctrl, const unsigned* __restrict__ candC,
        const unsigned* __restrict__ candB, float* __restrict__ medp) {
    __shared__ unsigned h2[2048];
    __shared__ unsigned tmp[256];
    __shared__ unsigned res[2];
    const unsigned covered = ctrl[4];
    const unsigned* src = covered ? candC : candB;
    unsigned M = covered ? ctrl[6] : ctrl[5];
    if (M > CAND_CAP) M = CAND_CAP;
    const unsigned bucket = ctrl[0];
    const unsigned r = ctrl[1];

    // Level 2: key bits [20:10]
    for (int i = threadIdx.x; i < 2048; i += 256) h2[i] = 0;
    __syncthreads();
    for (unsigned i = threadIdx.x; i < M; i += 256) {
        unsigned key = src[i];
        if ((key >> 21) == bucket) atomicAdd(&h2[(key >> 10) & 0x7FFu], 1u);
    }
    __syncthreads();
    find_crossing<8>(h2, r, tmp, res);
    const unsigned pref = (bucket << 11) | res[0];
    const unsigned r2 = res[1];
    __syncthreads();

    // Level 3: key bits [9:0]
    for (int i = threadIdx.x; i < 1024; i += 256) h2[i] = 0;
    __syncthreads();
    for (unsigned i = threadIdx.x; i < M; i += 256) {
        unsigned key = src[i];
        if ((key >> 10) == pref) atomicAdd(&h2[key & 0x3FFu], 1u);
    }
    __syncthreads();
    find_crossing<4>(h2, r2, tmp, res);
    if (threadIdx.x == 0) {
        unsigned key = (pref << 10) | res[0];
        unsigned u = (key & 0x80000000u) ? (key ^ 0x80000000u) : ~key;
        *medp = __uint_as_float(u);
    }
}

// ---- Fused threshold + 7x7 maxpool + NMS: all-b128 LDS, bank-optimal strides ----
// (Round-4 structure: horizontal-first separable max. Verified conflict-free:
//  every wave b128 access pattern hits each bank exactly 8 times. The
//  vertical-first variant is structurally 4-way conflicted — 8-row separation
//  x any float4-aligned stride is ≡ 0 mod 32 banks. Do not switch back.)
// Tile: 64 wide x 32 tall. Halo tile: 38 rows x 72 cols (gx in [tx0-4, tx0+68)).
// Output col j <-> sin col j+4; horizontal window for out j = sin cols j+1..j+7.
__global__ __launch_bounds__(256, 6) void nms_kernel(const float* __restrict__ x,
                                                     float* __restrict__ out,
                                                     const float* __restrict__ medp) {
    __shared__ __align__(16) float sin_[TILE_H * SIN_STR];  // 38x76 dwords = 11.5 KB
    __shared__ __align__(16) float shm[TILE_H * SHM_STR];   // 38x68 dwords = 10.3 KB
    const float med = *medp;
    const int tx0 = blockIdx.x * TX;
    const int ty0 = blockIdx.y * TY;
    const size_t ib = (size_t)blockIdx.z * (size_t)(IMG_H * IMG_W);
    const float* img = x + ib;
    float* oimg = out + ib;
    const bool colsafe = (tx0 >= 4) && (tx0 + 68 <= IMG_W);

    // Phase 1: load 38x72 halo tile as float4, threshold on the fly.
    // Out-of-image -> -inf (pool padding; thr >= 0 so it never wins).
    for (int task = threadIdx.x; task < TILE_H * 18; task += 256) {
        int rr = task / 18;
        int c4 = task - rr * 18;
        int gy = ty0 + rr - HALO;
        int gx0 = tx0 - 4 + c4 * 4;
        float4 v;
        if ((unsigned)gy < (unsigned)IMG_H) {
            if (colsafe) {
                v = *(const float4*)(img + (size_t)gy * IMG_W + gx0);
                v.x = (v.x > med) ? v.x : 0.0f;
                v.y = (v.y > med) ? v.y : 0.0f;
                v.z = (v.z > med) ? v.z : 0.0f;
                v.w = (v.w > med) ? v.w : 0.0f;
            } else {
                float c[4];
#pragma unroll
                for (int j = 0; j < 4; ++j) {
                    int gx = gx0 + j;
                    if ((unsigned)gx < (unsigned)IMG_W) {
                        float xv = img[(size_t)gy * IMG_W + gx];
                        c[j] = (xv > med) ? xv : 0.0f;
                    } else c[j] = -INFINITY;
                }
                v = make_float4(c[0], c[1], c[2], c[3]);
            }
        } else {
            v = make_float4(-INFINITY, -INFINITY, -INFINITY, -INFINITY);
        }
        *(float4*)&sin_[rr * SIN_STR + c4 * 4] = v;
    }
    __syncthreads();

    // Phase 2: horizontal 7-tap max. 38 rows x 4 segments of 16 outputs.
    // 6 aligned b128 reads -> 16 outputs -> 4 aligned b128 writes.
    for (int task = threadIdx.x; task < TILE_H * 4; task += 256) {
        int rr = task >> 2;
        int s = task & 3;
        int c0 = s * 16;
        const float* p = &sin_[rr * SIN_STR + c0];
        float v[24];
#pragma unroll
        for (int b = 0; b < 6; ++b) {
            float4 q = *(const float4*)(p + 4 * b);
            v[4 * b] = q.x; v[4 * b + 1] = q.y; v[4 * b + 2] = q.z; v[4 * b + 3] = q.w;
        }
        float m2[22];
#pragma unroll
        for (int j = 1; j <= 21; ++j) m2[j] = fmaxf(v[j], v[j + 1]);
        float m4[20];
#pragma unroll
        for (int j = 1; j <= 19; ++j) m4[j] = fmaxf(m2[j], m2[j + 2]);
        float o[16];
#pragma unroll
        for (int j = 0; j < 16; ++j) o[j] = fmaxf(m4[j + 1], m4[j + 4]);  // max sin[j+1..j+7]
        float* q = &shm[rr * SHM_STR + c0];
#pragma unroll
        for (int b = 0; b < 4; ++b)
            *(float4*)(q + 4 * b) = make_float4(o[4 * b], o[4 * b + 1], o[4 * b + 2], o[4 * b + 3]);
    }
    __syncthreads();

    // Phase 3: vertical 7-tap max on float4 columns + NMS compare + float4 stores.
    // Thread: col4 = t&15 (16 float4 cols), rseg = t>>4 (16 segs x 2 out rows).
    {
        const int col4 = threadIdx.x & 15;
        const int r0 = (threadIdx.x >> 4) * 2;
        float4 v[8];
#pragma unroll
        for (int j = 0; j < 8; ++j) v[j] = *(const float4*)&shm[(r0 + j) * SHM_STR + col4 * 4];
        float4 m2[7];
#pragma unroll
        for (int j = 0; j < 7; ++j) m2[j] = fmax4(v[j], v[j + 1]);
        float4 m4[5];
#pragma unroll
        for (int j = 0; j < 5; ++j) m4[j] = fmax4(m2[j], m2[j + 2]);
        float4 ma = fmax4(m4[0], m4[3]);  // rows r0..r0+6   -> out row r0
        float4 mb = fmax4(m4[1], m4[4]);  // rows r0+1..r0+7 -> out row r0+1
        float4 ta = *(const float4*)&sin_[(r0 + HALO) * SIN_STR + col4 * 4 + 4];
        float4 tb = *(const float4*)&sin_[(r0 + 1 + HALO) * SIN_STR + col4 * 4 + 4];
        float4 oa = make_float4((ta.x == ma.x) ? ta.x : 0.0f, (ta.y == ma.y) ? ta.y : 0.0f,
                                (ta.z == ma.z) ? ta.z : 0.0f, (ta.w == ma.w) ? ta.w : 0.0f);
        float4 ob = make_float4((tb.x == mb.x) ? tb.x : 0.0f, (tb.y == mb.y) ? tb.y : 0.0f,
                                (tb.z == mb.z) ? tb.z : 0.0f, (tb.w == mb.w) ? tb.w : 0.0f);
        *(float4*)(oimg + (size_t)(ty0 + r0) * IMG_W + tx0 + col4 * 4) = oa;
        *(float4*)(oimg + (size_t)(ty0 + r0 + 1) * IMG_W + tx0 + col4 * 4) = ob;
    }
}

extern "C" void kernel_launch(void* const* d_in, const int* in_sizes, int n_in,
                              void* d_out, int out_size, void* d_ws, size_t ws_size,
                              hipStream_t stream) {
    const float* x = (const float*)d_in[0];
    float* out = (float*)d_out;
    const int n = in_sizes[0];                   // 8*2048*2048
    const int n4 = n / 4;
    const unsigned k = (unsigned)((n - 1) / 2);  // lower-median rank (0-indexed)

    unsigned char* ws = (unsigned char*)d_ws;
    unsigned* ghist = (unsigned*)ws;               // 2048 u32
    unsigned* ctrl = (unsigned*)(ws + 2048 * 4);   // [0]=bucket [1]=rank [2]=cntA [3]=ovf [4]=covered [5]=cntB [6]=cntC
    float* medp = (float*)(ctrl + 7);
    unsigned* candA = (unsigned*)(ws + 2048 * 4 + 64);
    unsigned* candB = candA + CAND_CAP;
    unsigned* candC = candB + CAND_CAP;
    const size_t reserved = 2048 * 4 + 64;

    // ws is re-poisoned to 0xAA before every timed launch: zero hist + control words.
    hipMemsetAsync(d_ws, 0, reserved, stream);

    // Window around the expected median of ~N(0,1) data: |x| < 0.002 (~9 sigma of
    // the sample-median distribution at n=33.5M). Coverage is verified exactly;
    // fallback pass handles arbitrary inputs.
    const float W = 0.002f;
    const unsigned keyLo = f2key_host(-W);
    const unsigned keyHi = f2key_host(W);

    hist_window_kernel<<<1024, 256, 0, stream>>>((const float4*)x, n4, ghist, ctrl, candA, keyLo, keyHi);
    find_bucket_kernel<<<1, 256, 0, stream>>>(ghist, k, ctrl, keyLo, keyHi);
    compact_fallback_kernel<<<1024, 256, 0, stream>>>((const float4*)x, n4, ctrl, candB);
    bucket_filter_kernel<<<64, 256, 0, stream>>>(ctrl, ctrl, candA, candC);
    final_select_kernel<<<1, 256, 0, stream>>>(ctrl, candC, candB, medp);

    dim3 grid(IMG_W / TX, IMG_H / TY, n / (IMG_H * IMG_W));
    nms_kernel<<<grid, 256, 0, stream>>>(x, out, medp);
}